// Round 10
// baseline (2896.187 us; speedup 1.0000x reference)
//
#include <hip/hip_runtime.h>
#include <cstdint>
#include <cstddef>

#define HID 64
#define RPG 16          // batch rows per block = MFMA N-tile (swapped form)
#define HSTR 72         // ushorts per h row: 144 B (16B-aligned)
#define XSTR 68         // floats per x row: 272 B (16B-aligned)

typedef short bf16x8 __attribute__((ext_vector_type(8)));
typedef float f32x4 __attribute__((ext_vector_type(4)));

// Exact-erf GELU via Abramowitz & Stegun 7.1.26 (max |erf err| ~1.5e-7).
// exp(-u^2) computed as exp2(-(u*sqrt(log2e))^2) — one fewer mul.
__device__ __forceinline__ float fast_gelu(float z) {
    float u = z * 0.70710678118654752f;
    float a = __builtin_fabsf(u);
    float t = __builtin_amdgcn_rcpf(__builtin_fmaf(0.3275911f, a, 1.0f));
    float s = u * 1.20112240878645f;            // sqrt(log2 e)
    float e = __builtin_amdgcn_exp2f(-(s * s)); // exp(-u^2)
    float p =                   1.061405429f;
    p = __builtin_fmaf(p, t, -1.453152027f);
    p = __builtin_fmaf(p, t,  1.421413741f);
    p = __builtin_fmaf(p, t, -0.284496736f);
    p = __builtin_fmaf(p, t,  0.254829592f);
    p = p * t;
    float er = __builtin_fmaf(-p, e, 1.0f);
    er = __builtin_copysignf(er, u);
    float zh = 0.5f * z;
    return __builtin_fmaf(zh, er, zh);
}

__device__ __forceinline__ ushort bf16_hi(float f) {
    return (ushort)(__float_as_uint(f) >> 16);
}
__device__ __forceinline__ float bf16_f(ushort u) {
    return __uint_as_float(((unsigned)u) << 16);
}

// Pack top halves of two f32 bit-patterns into one u32: {lo16=a>>16, hi16=b>>16}.
#define PKHI(b_, a_) __builtin_amdgcn_perm((b_), (a_), 0x07060302u)

// One step, swapped form: D'[c'][r] = sum_k W^T[c'][k] h[k][r].
// A = W^T (static regs), B = h read [r][k] row-major (4x ds_read_b128).
// C/D: col=lane&15 = r (fixed rr), row = 4q+e = c -> this lane's 4 outputs are
// CONTIGUOUS in c. Wave finishes ALL 4 elements; writes hi/lo planes as one
// ds_write_b64 each. One barrier per step.
#define STEP(RHI, RLO, WHI, WLO, XB) { \
    const bf16x8 Hhi0 = *reinterpret_cast<const bf16x8*>(RHI); \
    const bf16x8 Hhi1 = *reinterpret_cast<const bf16x8*>((RHI) + 32); \
    const bf16x8 Hlo0 = *reinterpret_cast<const bf16x8*>(RLO); \
    const bf16x8 Hlo1 = *reinterpret_cast<const bf16x8*>((RLO) + 32); \
    const f32x4 zz = {0.f, 0.f, 0.f, 0.f}; \
    f32x4 ahh = __builtin_amdgcn_mfma_f32_16x16x32_bf16(Whi0, Hhi0, zz, 0, 0, 0); \
    f32x4 ac1 = __builtin_amdgcn_mfma_f32_16x16x32_bf16(Whi0, Hlo0, zz, 0, 0, 0); \
    f32x4 ac2 = __builtin_amdgcn_mfma_f32_16x16x32_bf16(Wlo0, Hhi0, zz, 0, 0, 0); \
    ahh = __builtin_amdgcn_mfma_f32_16x16x32_bf16(Whi1, Hhi1, ahh, 0, 0, 0); \
    ac1 = __builtin_amdgcn_mfma_f32_16x16x32_bf16(Whi1, Hlo1, ac1, 0, 0, 0); \
    ac2 = __builtin_amdgcn_mfma_f32_16x16x32_bf16(Wlo1, Hhi1, ac2, 0, 0, 0); \
    const float z0 = (ahh[0] + ac1[0]) + (ac2[0] + __builtin_fmaf((XB), win0, cb0)); \
    const float z1 = (ahh[1] + ac1[1]) + (ac2[1] + __builtin_fmaf((XB), win1, cb1)); \
    const float z2 = (ahh[2] + ac1[2]) + (ac2[2] + __builtin_fmaf((XB), win2, cb2)); \
    const float z3 = (ahh[3] + ac1[3]) + (ac2[3] + __builtin_fmaf((XB), win3, cb3)); \
    const float h0 = fast_gelu(z0); \
    const float h1 = fast_gelu(z1); \
    const float h2 = fast_gelu(z2); \
    const float h3 = fast_gelu(z3); \
    const unsigned hb0 = __float_as_uint(h0), hb1 = __float_as_uint(h1); \
    const unsigned hb2 = __float_as_uint(h2), hb3 = __float_as_uint(h3); \
    uint2 hpk; hpk.x = PKHI(hb1, hb0); hpk.y = PKHI(hb3, hb2); \
    *(WHI) = hpk; \
    const unsigned lb0 = __float_as_uint(h0 - __uint_as_float(hb0 & 0xffff0000u)); \
    const unsigned lb1 = __float_as_uint(h1 - __uint_as_float(hb1 & 0xffff0000u)); \
    const unsigned lb2 = __float_as_uint(h2 - __uint_as_float(hb2 & 0xffff0000u)); \
    const unsigned lb3 = __float_as_uint(h3 - __uint_as_float(hb3 & 0xffff0000u)); \
    uint2 lpk; lpk.x = PKHI(lb1, lb0); lpk.y = PKHI(lb3, lb2); \
    *(WLO) = lpk; \
    __syncthreads(); }

__global__ __launch_bounds__(256, 1)
void ssm_kernel(const float* __restrict__ x,
                const float* __restrict__ W_in,
                const float* __restrict__ b_in,
                const float* __restrict__ W_s,
                const float* __restrict__ b_s,
                const float* __restrict__ W_out,
                const float* __restrict__ b_out,
                float* __restrict__ out,
                int B, int T) {
    // h state split-bf16, ping-pong, [r][k] row-major: hlds[pp][hi/lo][r*HSTR + k]
    __shared__ ushort hlds[2][2][RPG * HSTR];
    __shared__ float  xlds[RPG][XSTR];             // x[r][t_local], padded rows

    const int tid  = threadIdx.x;
    const int g    = tid >> 6;        // wave 0..3: owns c-tile [16g, 16g+16)
    const int lane = tid & 63;
    const int q    = lane >> 4;
    const int rr   = lane & 15;       // this lane's batch row (C col-index)
    const int bA   = blockIdx.x * RPG;
    const int cq   = 16 * g + 4 * q;  // c-quad base this lane produces

    if (bA >= B) return;

    // A-operand = W^T tile g (static): lane rr holds W^T[c'=rr][k=8q+e].
    bf16x8 Whi0, Whi1, Wlo0, Wlo1;
    const int wcol = 16 * g + rr;
#pragma unroll
    for (int e = 0; e < 8; ++e) {
        {   const float wf = W_s[(8 * q + e) * HID + wcol];
            const ushort hi = bf16_hi(wf);
            Whi0[e] = (short)hi;
            Wlo0[e] = (short)bf16_hi(wf - bf16_f(hi)); }
        {   const float wf = W_s[(32 + 8 * q + e) * HID + wcol];
            const ushort hi = bf16_hi(wf);
            Whi1[e] = (short)hi;
            Wlo1[e] = (short)bf16_hi(wf - bf16_f(hi)); }
    }
    // Pin in VGPRs (round-1 lesson: const global loads get rematerialized).
    asm volatile("" : "+v"(Whi0), "+v"(Whi1), "+v"(Wlo0), "+v"(Wlo1));

    // Per-element input-projection constants for this lane's c-quad.
    const float win0 = W_in[cq + 0], win1 = W_in[cq + 1];
    const float win2 = W_in[cq + 2], win3 = W_in[cq + 3];
    const float cb0 = b_in[cq + 0] + b_s[cq + 0];
    const float cb1 = b_in[cq + 1] + b_s[cq + 1];
    const float cb2 = b_in[cq + 2] + b_s[cq + 2];
    const float cb3 = b_in[cq + 3] + b_s[cq + 3];

    // zero h(pp=0); ordered before first read by the staging barrier below
    {
        ushort* p = &hlds[0][0][0];
        for (int i = tid; i < 2 * RPG * HSTR; i += 256) p[i] = 0;
    }

    // Loop-invariant LDS pointers.
    const ushort* const rhiA = &hlds[0][0][rr * HSTR + 8 * q];
    const ushort* const rloA = &hlds[0][1][rr * HSTR + 8 * q];
    const ushort* const rhiB = &hlds[1][0][rr * HSTR + 8 * q];
    const ushort* const rloB = &hlds[1][1][rr * HSTR + 8 * q];
    uint2* const whiA = reinterpret_cast<uint2*>(&hlds[0][0][rr * HSTR + cq]);
    uint2* const wloA = reinterpret_cast<uint2*>(&hlds[0][1][rr * HSTR + cq]);
    uint2* const whiB = reinterpret_cast<uint2*>(&hlds[1][0][rr * HSTR + cq]);
    uint2* const wloB = reinterpret_cast<uint2*>(&hlds[1][1][rr * HSTR + cq]);

    const int nch = T >> 6;           // T multiple of 64 (8192 here)

    for (int tc = 0; tc < nch; ++tc) {
        // Stage x[bA..bA+16)[tc*64..+64): one float4 per thread, coalesced.
        {
            const int row = tid >> 4;         // 0..15
            const int ch  = tid & 15;         // 0..15 -> 4 floats each
            const float4 xg = *reinterpret_cast<const float4*>(
                &x[(size_t)(bA + row) * (size_t)T + (size_t)(tc * 64 + ch * 4)]);
            *reinterpret_cast<float4*>(&xlds[row][ch * 4]) = xg;
        }
        __syncthreads();

#pragma unroll 1
        for (int t4 = 0; t4 < 16; ++t4) {
            const f32x4 xq = *reinterpret_cast<const f32x4*>(&xlds[rr][t4 * 4]);
            STEP(rhiA, rloA, whiB, wloB, xq[0])
            STEP(rhiB, rloB, whiA, wloA, xq[1])
            STEP(rhiA, rloA, whiB, wloB, xq[2])
            STEP(rhiB, rloB, whiA, wloA, xq[3])
        }
    }

    // Epilogue: h final in hlds[0] (even step count). out[b] = h.W_out + b_out.
    if (g == 0) {
        const int r  = lane >> 2;
        const int p4 = lane & 3;
        const ushort* hp = &hlds[0][0][r * HSTR + p4 * 16];
        const ushort* lp = &hlds[0][1][r * HSTR + p4 * 16];
        float s = 0.f;
#pragma unroll
        for (int j = 0; j < 16; ++j)
            s = __builtin_fmaf(bf16_f(hp[j]) + bf16_f(lp[j]), W_out[p4 * 16 + j], s);
        s += __shfl_xor(s, 1, 64);
        s += __shfl_xor(s, 2, 64);
        if (p4 == 0) out[bA + r] = s + b_out[0];
    }
}

extern "C" void kernel_launch(void* const* d_in, const int* in_sizes, int n_in,
                              void* d_out, int out_size, void* d_ws, size_t ws_size,
                              hipStream_t stream) {
    const float* x     = (const float*)d_in[0];
    const float* W_in  = (const float*)d_in[1];
    const float* b_in  = (const float*)d_in[2];
    const float* W_s   = (const float*)d_in[3];
    const float* b_s   = (const float*)d_in[4];
    const float* W_out = (const float*)d_in[5];
    const float* b_out = (const float*)d_in[6];
    float* out = (float*)d_out;

    const int B = out_size;                 // [B,1] output
    const int T = in_sizes[0] / B;          // x is [B,T,1]

    const int blocks = B / RPG;             // 256 for B=4096
    ssm_kernel<<<blocks, 256, 0, stream>>>(
        x, W_in, b_in, W_s, b_s, W_out, b_out, out, B, T);
}